// Round 7
// baseline (230.658 us; speedup 1.0000x reference)
//
#include <hip/hip_runtime.h>

// Sizes (fixed by the problem)
#define L_ 128       // B*C
#define N_ 256
#define M_ 131072    // D*H*W
// Analytic facts used:
// 1) Sinkhorn: u = v = 1/100 exactly (fp32); T = exp(-0.1*cost) * 1e-4.
// 2) Interp uses only aligned[:, 4j+1], [:, 4j+2] (weights 0.5/0.5):
//    nu in [0,128): n = 4*(nu>>1)+1+(nu&1).
// R11: 3-dispatch pipeline. k_prep folded into k_gemm (text self-staged via
// the v1/uu LDS region; anorm fp32 at stage time). k_p1 folded into k_fuse2
// (P1 recomputed per block from TLT + w1 — 0.4us). k_gemm: pack-on-stage
// (no fp32 raw LDS round trip), separate w16 buffer (4 barriers/step).

using short8  = __attribute__((ext_vector_type(8)))  short;
using floatx16 = __attribute__((ext_vector_type(16))) float;

__device__ __forceinline__ unsigned short f2bf(float f) {
  unsigned u = __float_as_uint(f);
  u += 0x7fffu + ((u >> 16) & 1u);       // RN-even
  return (unsigned short)(u >> 16);
}
__device__ __forceinline__ float bf2f(unsigned short s) {
  return __uint_as_float(((unsigned)s) << 16);
}
__device__ __forceinline__ unsigned pack2(float x, float y) {
  return ((unsigned)f2bf(y) << 16) | (unsigned)f2bf(x);   // low = first k-elem
}
__device__ __forceinline__ floatx16 mm(uint4 a, uint4 b, floatx16 c) {
  return __builtin_amdgcn_mfma_f32_32x32x16_bf16(
      __builtin_bit_cast(short8, a), __builtin_bit_cast(short8, b), c, 0, 0, 0);
}

// ------------------------------------------------------------------- k_gemm
// LDS layout (u32 indices into SH):
//   v1   @ 0      [128 l][36]  bf16 m-pairs (stage output, GEMM2 A-src)
//   uu   @ 4608   [64 m][68]   bf16 l-pairs (GEMM1 B-src, imf_Tp source)
//   w16  @ 8960   [128 nu][72] u16 W-tile  (GEMM2 B-src; an_part in prologue)
//   bnp  @ 13568  [4][64] f32  per-wave bnorm partials
//   anu  @ 13824  [128] f32    anorm
// total 13952 u32 = 55.8 KB -> 2 blocks/CU.
__global__ __launch_bounds__(256, 2) void k_gemm(
    const float* __restrict__ image, const float* __restrict__ text,
    unsigned* __restrict__ imf_Tp, unsigned short* __restrict__ pbuf) {
  __shared__ unsigned SH[13952];
  float* SHf = (float*)SH;
  unsigned* v1 = SH;
  unsigned* uu = SH + 4608;
  unsigned short* w16 = (unsigned short*)(SH + 8960);
  const int t = threadIdx.x;
  const int lane = t & 63, w = t >> 6;
  const int q = lane >> 5, r = lane & 31;
  const int wnu = w >> 1, wm = w & 1;   // GEMM1 wave tile: [64 nu x 32 m]
  const int wl = w >> 1, wn = w & 1;    // GEMM2 wave tile: [64 l x 64 nu]
  const int m_base = blockIdx.x * 256;

  // ---- prologue phase 0: stage textp into SH[0..8191] + anorm partials
  {
    const int nuh = t & 127, half = t >> 7;
    const int n = 4 * (nuh >> 1) + 1 + (nuh & 1);
    float sq = 0.f;
#pragma unroll 8
    for (int j = 0; j < 32; ++j) {
      const int l0 = half * 64 + 2 * j;
      const float x = text[l0 * N_ + n];
      const float y = text[(l0 + 1) * N_ + n];
      sq = fmaf(x, x, fmaf(y, y, sq));
      SH[nuh * 64 + half * 32 + j] = pack2(x, y);
    }
    ((float*)w16)[nuh * 2 + half] = sq;   // an_part in w16 region
  }
  __syncthreads();
  // ---- prologue phase 1: at[] register frags + anorm finalize
  uint4 at[2][8];
#pragma unroll
  for (int nt = 0; nt < 2; ++nt)
#pragma unroll
    for (int kk = 0; kk < 8; ++kk)
      at[nt][kk] = *(const uint4*)&SH[(wnu * 64 + nt * 32 + r) * 64 + kk * 8 + q * 4];
  if (t < 128)
    SHf[13824 + t] = ((float*)w16)[t * 2] + ((float*)w16)[t * 2 + 1];

  floatx16 zz;
#pragma unroll
  for (int i = 0; i < 16; ++i) zz[i] = 0.f;
  floatx16 acc2[2][2] = {zz, zz, zz, zz};

  const int rowg = t >> 4;              // stage: row group (16 rows/iter set)
  const int mqi = t & 15;               // stage: m-quad index
  const int mq = mqi * 4;

  for (int s = 0; s < 4; ++s) {
    const int msub = m_base + s * 64;
    __syncthreads();                    // sync1: prev reads of v1/uu/w16 done
    // ---- stage: image float4 -> bf16 m-pairs into v1 + fp32 sq accum
    float sq0 = 0.f, sq1 = 0.f, sq2 = 0.f, sq3 = 0.f;
#pragma unroll
    for (int i = 0; i < 8; ++i) {
      const int l = rowg + 16 * i;
      const float4 v = *(const float4*)&image[(size_t)l * M_ + msub + mq];
      sq0 = fmaf(v.x, v.x, sq0);
      sq1 = fmaf(v.y, v.y, sq1);
      sq2 = fmaf(v.z, v.z, sq2);
      sq3 = fmaf(v.w, v.w, sq3);
      uint2 pr; pr.x = pack2(v.x, v.y); pr.y = pack2(v.z, v.w);
      *(uint2*)&v1[l * 36 + (mq >> 1)] = pr;
    }
    // bnorm partials: reduce 4 rowg-groups within wave, store per-wave
    sq0 += __shfl_xor(sq0, 16); sq0 += __shfl_xor(sq0, 32);
    sq1 += __shfl_xor(sq1, 16); sq1 += __shfl_xor(sq1, 32);
    sq2 += __shfl_xor(sq2, 16); sq2 += __shfl_xor(sq2, 32);
    sq3 += __shfl_xor(sq3, 16); sq3 += __shfl_xor(sq3, 32);
    if (lane < 16) {
      SHf[13568 + w * 64 + mq + 0] = sq0;
      SHf[13568 + w * 64 + mq + 1] = sq1;
      SHf[13568 + w * 64 + mq + 2] = sq2;
      SHf[13568 + w * 64 + mq + 3] = sq3;
    }
    __syncthreads();                    // sync2: v1 + bnp ready
    // ---- build uu[m][lp] from v1 (bit-repack, lanes = m: conflict-free reads)
    {
      const int m = t & 63;
      const bool modd = (m & 1) != 0;
#pragma unroll
      for (int j = 0; j < 16; ++j) {
        const int lp = w * 16 + j;
        const unsigned a = v1[(2 * lp) * 36 + (m >> 1)];
        const unsigned c = v1[(2 * lp + 1) * 36 + (m >> 1)];
        uu[m * 68 + lp] = modd ? ((a >> 16) | (c & 0xffff0000u))
                               : ((a & 0xffffu) | (c << 16));
      }
    }
    __syncthreads();                    // sync3: uu ready
    // ---- imf_Tp global copy (2KB-contiguous bursts per instruction)
#pragma unroll
    for (int i = 0; i < 8; ++i) {
      const int m = i * 8 + (t >> 5);
      const int p = t & 31;
      const uint2 o = *(const uint2*)&uu[m * 68 + 2 * p];
      *(uint2*)&imf_Tp[(size_t)(msub + m) * 64 + 2 * p] = o;
    }
    // ---- GEMM1: cost dots [128 nu x 64 m], K = 128 (l)
    floatx16 acc1[2] = {zz, zz};
#pragma unroll
    for (int kk = 0; kk < 8; ++kk) {
      const uint4 bv = *(const uint4*)&uu[(wm * 32 + r) * 68 + kk * 8 + q * 4];
      acc1[0] = mm(at[0][kk], bv, acc1[0]);
      acc1[1] = mm(at[1][kk], bv, acc1[1]);
    }
    const int mloc = wm * 32 + r;
    const float bn = SHf[13568 + mloc] + SHf[13568 + 64 + mloc] +
                     SHf[13568 + 128 + mloc] + SHf[13568 + 192 + mloc];
#pragma unroll
    for (int nt = 0; nt < 2; ++nt)
#pragma unroll
      for (int reg = 0; reg < 16; ++reg) {
        const int nu = wnu * 64 + nt * 32 + (reg & 3) + 8 * (reg >> 2) + 4 * q;
        const float d2 = SHf[13824 + nu] + bn - 2.0f * acc1[nt][reg];
        const float cst = sqrtf(fmaxf(d2, 0.0f));
        w16[nu * 72 + mloc] = f2bf(__expf(-0.1f * cst) * 1e-4f);
      }
    __syncthreads();                    // sync4: w16 ready
    // ---- GEMM2: acc2[l][nu] += imf @ Wt, K = 64 (m)
#pragma unroll
    for (int kk2 = 0; kk2 < 4; ++kk2) {
      const uint4 a0 = *(const uint4*)&v1[(wl * 64 + r) * 36 + kk2 * 8 + q * 4];
      const uint4 a1 = *(const uint4*)&v1[(wl * 64 + 32 + r) * 36 + kk2 * 8 + q * 4];
      const uint4 b0 = *(const uint4*)&((unsigned*)w16)[(wn * 64 + r) * 36 + kk2 * 8 + q * 4];
      const uint4 b1 = *(const uint4*)&((unsigned*)w16)[(wn * 64 + 32 + r) * 36 + kk2 * 8 + q * 4];
      acc2[0][0] = mm(a0, b0, acc2[0][0]);
      acc2[0][1] = mm(a0, b1, acc2[0][1]);
      acc2[1][0] = mm(a1, b0, acc2[1][0]);
      acc2[1][1] = mm(a1, b1, acc2[1][1]);
    }
  }
#pragma unroll
  for (int lt = 0; lt < 2; ++lt)
#pragma unroll
    for (int nt2 = 0; nt2 < 2; ++nt2)
#pragma unroll
      for (int reg = 0; reg < 16; ++reg) {
        const int l = wl * 64 + lt * 32 + (reg & 3) + 8 * (reg >> 2) + 4 * q;
        const int nu = wn * 64 + nt2 * 32 + r;
        pbuf[((size_t)blockIdx.x * 128 + l) * 128 + nu] = f2bf(acc2[lt][nt2][reg]);
      }
}

// ----------------------------- reduce partials + interp (weights exactly 0.5)
__global__ __launch_bounds__(256) void k_tline(const unsigned short* __restrict__ pbuf,
                                               float* __restrict__ tline) {
  __shared__ float red[2][4][64];
  const int t = threadIdx.x;
  const int l = blockIdx.x;
  const int j = t & 63, part = t >> 6;
  float s1 = 0.f, s2 = 0.f;
  for (int b = part; b < 512; b += 4) {
    const unsigned v = *(const unsigned*)&pbuf[((size_t)b * 128 + l) * 128 + 2 * j];
    s1 += bf2f((unsigned short)(v & 0xffffu));
    s2 += bf2f((unsigned short)(v >> 16));
  }
  red[0][part][j] = s1; red[1][part][j] = s2;
  __syncthreads();
  if (t < 64) {
    float S1 = 0.f, S2 = 0.f;
#pragma unroll
    for (int p = 0; p < 4; ++p) { S1 += red[0][p][t]; S2 += red[1][p][t]; }
    tline[l * 64 + t] = S1 * 0.5f + S2 * 0.5f;
  }
}

// ------------------------------------- k_fuse2: MFMA voxel MLP + gated fusion
// R11: self-packs w1/w2 fragments from global; computes P1 in-block from TLT.
__global__ __launch_bounds__(256) void k_fuse2(
    const unsigned* __restrict__ imf_Tp, const float* __restrict__ w1,
    const float* __restrict__ b1, const float* __restrict__ w2,
    const float* __restrict__ b2, const float* __restrict__ tline,
    float* __restrict__ out) {
  __shared__ float P1T[64 * 66];      // [w][c], stride 66 (2-way = free)
  __shared__ float TLT[64 * 66];      // [w][o]
  __shared__ unsigned hb[4 * 32 * 34];  // per-wave [m][kp], stride 34
  __shared__ float b2s[64];
  const int t = threadIdx.x;
  const int lane = t & 63, wv = t >> 6;
  const int q = lane >> 5, r = lane & 31;
  const int b = blockIdx.x >> 8;
  const int chunk = blockIdx.x & 255;
  unsigned* __restrict__ hbw = hb + wv * (32 * 34);

  for (int i = t; i < 4096; i += 256) {
    const int c = i >> 6, ww = i & 63;
    TLT[ww * 66 + c] = tline[b * 4096 + i];
  }
  if (t < 64) b2s[t] = b2[t];

  // pack weight fragments from global (w1 second-half cols; w2 full)
  uint4 w1f[2][4], w2f[2][4];
#pragma unroll
  for (int ct = 0; ct < 2; ++ct)
#pragma unroll
    for (int s = 0; s < 4; ++s) {
      const int kp0 = s * 8 + q * 4;
      const float* w1r = w1 + (ct * 32 + r) * 128 + 64 + 2 * kp0;
      const float* w2r = w2 + (ct * 32 + r) * 64 + 2 * kp0;
      float2 u0 = *(const float2*)(w1r + 0), u1 = *(const float2*)(w1r + 2);
      float2 u2 = *(const float2*)(w1r + 4), u3 = *(const float2*)(w1r + 6);
      uint4 f1; f1.x = pack2(u0.x, u0.y); f1.y = pack2(u1.x, u1.y);
      f1.z = pack2(u2.x, u2.y); f1.w = pack2(u3.x, u3.y);
      w1f[ct][s] = f1;
      u0 = *(const float2*)(w2r + 0); u1 = *(const float2*)(w2r + 2);
      u2 = *(const float2*)(w2r + 4); u3 = *(const float2*)(w2r + 6);
      uint4 f2; f2.x = pack2(u0.x, u0.y); f2.y = pack2(u1.x, u1.y);
      f2.z = pack2(u2.x, u2.y); f2.w = pack2(u3.x, u3.y);
      w2f[ct][s] = f2;
    }
  __syncthreads();                      // TLT ready
  // ---- compute P1T[w][o] = b1[o] + sum_c w1[o][c] * TLT[w][c]
  {
    const int ww = t & 63;
#pragma unroll
    for (int og = 0; og < 16; ++og) {
      const int o = (t >> 6) * 16 + og;
      float acc = b1[o];
      const float* w1r = w1 + o * 128;
#pragma unroll 8
      for (int c = 0; c < 64; ++c) acc = fmaf(w1r[c], TLT[ww * 66 + c], acc);
      P1T[ww * 66 + o] = acc;
    }
  }

  floatx16 zz;
#pragma unroll
  for (int i = 0; i < 16; ++i) zz[i] = 0.f;

  for (int pass = 0; pass < 4; ++pass) {
    const int mbase = chunk * 512 + pass * 128 + wv * 32;
    const int m = mbase + r;
    const int ww = m & 63;
    // ---- layer 1
    floatx16 d1[2] = {zz, zz};
#pragma unroll
    for (int s = 0; s < 4; ++s) {
      const uint4 bfr = *(const uint4*)&imf_Tp[(size_t)m * 64 + b * 32 + s * 8 + q * 4];
      d1[0] = mm(w1f[0][s], bfr, d1[0]);
      d1[1] = mm(w1f[1][s], bfr, d1[1]);
    }
    __syncthreads();   // hb WAR vs prev pass; also covers P1T RAW on pass 0
#pragma unroll
    for (int ct = 0; ct < 2; ++ct)
#pragma unroll
      for (int R = 0; R < 4; ++R) {
        const int cb = ct * 32 + 8 * R + 4 * q;          // rows cb..cb+3
        const float2 pa = *(const float2*)&P1T[ww * 66 + cb];
        const float2 pb = *(const float2*)&P1T[ww * 66 + cb + 2];
        const float h0 = fmaxf(d1[ct][R * 4 + 0] + pa.x, 0.f);
        const float h1 = fmaxf(d1[ct][R * 4 + 1] + pa.y, 0.f);
        const float h2 = fmaxf(d1[ct][R * 4 + 2] + pb.x, 0.f);
        const float h3 = fmaxf(d1[ct][R * 4 + 3] + pb.y, 0.f);
        const int kp0 = ct * 16 + 4 * R + 2 * q;         // even
        uint2 pr; pr.x = pack2(h0, h1); pr.y = pack2(h2, h3);
        *(uint2*)&hbw[r * 34 + kp0] = pr;
      }
    __syncthreads();   // hb RAW
    // ---- layer 2
    floatx16 d2[2] = {zz, zz};
#pragma unroll
    for (int s = 0; s < 4; ++s) {
      const uint2 hlo = *(const uint2*)&hbw[r * 34 + s * 8 + q * 4];
      const uint2 hhi = *(const uint2*)&hbw[r * 34 + s * 8 + q * 4 + 2];
      uint4 bfr2; bfr2.x = hlo.x; bfr2.y = hlo.y; bfr2.z = hhi.x; bfr2.w = hhi.y;
      d2[0] = mm(w2f[0][s], bfr2, d2[0]);
      d2[1] = mm(w2f[1][s], bfr2, d2[1]);
    }
    // ---- epilogue: gate + residual blend (iv from bf16 imf_Tp, L1-hot)
#pragma unroll
    for (int ot = 0; ot < 2; ++ot)
#pragma unroll
      for (int R = 0; R < 4; ++R) {
        const int ob = ot * 32 + 8 * R + 4 * q;
        const float2 ta = *(const float2*)&TLT[ww * 66 + ob];
        const float2 tb = *(const float2*)&TLT[ww * 66 + ob + 2];
        const float trs[4] = {ta.x, ta.y, tb.x, tb.y};
        const unsigned iv01 = imf_Tp[(size_t)m * 64 + b * 32 + (ob >> 1)];
        const unsigned iv23 = imf_Tp[(size_t)m * 64 + b * 32 + (ob >> 1) + 1];
        const float ivv[4] = {
            bf2f((unsigned short)(iv01 & 0xffffu)),
            bf2f((unsigned short)(iv01 >> 16)),
            bf2f((unsigned short)(iv23 & 0xffffu)),
            bf2f((unsigned short)(iv23 >> 16))};
#pragma unroll
        for (int j = 0; j < 4; ++j) {
          const int o = ob + j;
          const float g = d2[ot][R * 4 + j] + b2s[o];
          const float gate = 1.0f / (1.0f + __expf(-g));
          const size_t gidx = (size_t)(b * 64 + o) * M_ + m;
          out[gidx] = fmaf(gate, trs[j] - ivv[j], ivv[j]);
        }
      }
  }
}

// ---------------------------------------------------------------- launcher
extern "C" void kernel_launch(void* const* d_in, const int* in_sizes, int n_in,
                              void* d_out, int out_size, void* d_ws, size_t ws_size,
                              hipStream_t stream) {
  const float* text  = (const float*)d_in[0];
  const float* image = (const float*)d_in[1];
  const float* w1    = (const float*)d_in[2];
  const float* b1    = (const float*)d_in[3];
  const float* w2    = (const float*)d_in[4];
  const float* b2    = (const float*)d_in[5];
  float* out = (float*)d_out;

  char* ws = (char*)d_ws;
  unsigned short* pbuf = (unsigned short*)(ws);       // 16 MiB [512][128][128] bf16
  unsigned* imf_Tp  = (unsigned*)(ws + 33554432);     // 32 MiB [131072][64] u32
  float*    tline   = (float*)(ws + 67666432);        // 32 KiB [2][64][64]

  k_gemm <<<512,  256, 0, stream>>>(image, text, imf_Tp, pbuf);
  k_tline<<<128,  256, 0, stream>>>(pbuf, tline);
  k_fuse2<<<512,  256, 0, stream>>>(imf_Tp, w1, b1, w2, b2, tline, out);
}